// Round 1
// baseline (5029.926 us; speedup 1.0000x reference)
//
#include <hip/hip_runtime.h>
#include <hip/hip_fp16.h>

typedef unsigned short u16;
typedef unsigned int   u32;

#define B_   32
#define T_   2048
#define C_   256
#define H_   256
#define TC_  1024
#define M_   (B_*TC_)   // 32768

using bf16x8 = __attribute__((ext_vector_type(8))) short;
using f32x4  = __attribute__((ext_vector_type(4))) float;
typedef _Float16 f16x2 __attribute__((ext_vector_type(2)));

__device__ __forceinline__ u16 f2bf(float f) {
  u32 u = __float_as_uint(f);
  u32 r = u + 0x7fffu + ((u >> 16) & 1u);
  return (u16)(r >> 16);
}
__device__ __forceinline__ float sigmf(float x) { return 1.f / (1.f + __expf(-x)); }
// tanh(x) = 1 - 2/(e^{2x}+1); exact limits at +-inf, ~1e-7 rel error
__device__ __forceinline__ float tanhfast(float x) {
  float e = __expf(2.f * x);
  return 1.f - 2.f / (e + 1.f);
}
__device__ __forceinline__ float dot2(u32 w, u32 h, float acc) {
  return __builtin_amdgcn_fdot2(__builtin_bit_cast(f16x2, w),
                                __builtin_bit_cast(f16x2, h), acc, false);
}

// ---------------- casts ----------------
__global__ void cast_bf16_kernel(const float* __restrict__ src, u16* __restrict__ dst, int n) {
  int i = blockIdx.x * 256 + threadIdx.x;
  if (i < n) dst[i] = f2bf(src[i]);
}
__global__ void cast_f16_kernel(const float* __restrict__ src, u16* __restrict__ dst, int n) {
  int i = blockIdx.x * 256 + threadIdx.x;
  if (i < n) dst[i] = __half_as_ushort(__float2half(src[i]));
}

// ---------------- conv + bn + relu -> y bf16 (B*TC, C) ----------------
__global__ __launch_bounds__(256)
void conv_bn_kernel(const float* __restrict__ x, const float* __restrict__ cw,
                    const float* __restrict__ cb, const float* __restrict__ bng,
                    const float* __restrict__ bnb, const float* __restrict__ bnm,
                    const float* __restrict__ bnv, u16* __restrict__ ybf) {
  int c = threadIdx.x;
  int bt = blockIdx.x;                  // b*TC + t
  int t = bt & (TC_ - 1), b = bt >> 10;
  const float* xr = x + (size_t)b * T_;
  float xm1 = (t > 0) ? xr[2 * t - 1] : 0.f;
  float x0 = xr[2 * t], xp1 = xr[2 * t + 1];
  float w0 = cw[c * 3], w1 = cw[c * 3 + 1], w2 = cw[c * 3 + 2];
  float inv = bng[c] * rsqrtf(bnv[c] + 1e-5f);
  float beta = bnb[c] - bnm[c] * inv;
  float v = w0 * xm1 + w1 * x0 + w2 * xp1 + cb[c];
  v = v * inv + beta;
  v = fmaxf(v, 0.f);
  ybf[(size_t)bt * C_ + c] = f2bf(v);
}

// ---------------- projection GEMM v2: LDS-staged 128x128 tile ----------------
#define PBK 32
#define APAD 8
__global__ __launch_bounds__(256)
void proj_gemm2_kernel(const u16* __restrict__ A,
                       const u16* __restrict__ Wf, const u16* __restrict__ Wr,
                       const float* __restrict__ bf, const float* __restrict__ br,
                       float* __restrict__ outf, float* __restrict__ outr,
                       int K) {
  const u16* W = blockIdx.z ? Wr : Wf;
  const float* bias = blockIdx.z ? br : bf;
  float* out = blockIdx.z ? outr : outf;
  __shared__ u16 As[128][PBK + APAD];
  __shared__ u16 Ws[128][PBK + APAD];
  const int tid = threadIdx.x;
  const int wave = tid >> 6, lane = tid & 63;
  const int l16 = lane & 15, quad = lane >> 4;
  const int m0 = blockIdx.x * 128, n0 = blockIdx.y * 128;
  const int wm = (wave >> 1) * 64, wn = (wave & 1) * 64;
  const int srow = tid >> 2, scol = (tid & 3) * 8;
  const u16* Ag0 = A + (size_t)(m0 + srow) * K + scol;
  const u16* Ag1 = Ag0 + (size_t)64 * K;
  const u16* Wg0 = W + (size_t)(n0 + srow) * K + scol;
  const u16* Wg1 = Wg0 + (size_t)64 * K;
  f32x4 acc[4][4] = {};
  for (int k0 = 0; k0 < K; k0 += PBK) {
    *(uint4*)&As[srow][scol]      = *(const uint4*)(Ag0 + k0);
    *(uint4*)&As[srow + 64][scol] = *(const uint4*)(Ag1 + k0);
    *(uint4*)&Ws[srow][scol]      = *(const uint4*)(Wg0 + k0);
    *(uint4*)&Ws[srow + 64][scol] = *(const uint4*)(Wg1 + k0);
    __syncthreads();
    bf16x8 af[4], wf[4];
#pragma unroll
    for (int i = 0; i < 4; ++i) {
      af[i] = *(const bf16x8*)&As[wm + 16 * i + l16][quad * 8];
      wf[i] = *(const bf16x8*)&Ws[wn + 16 * i + l16][quad * 8];
    }
#pragma unroll
    for (int i = 0; i < 4; ++i)
#pragma unroll
      for (int j = 0; j < 4; ++j)
        acc[i][j] = __builtin_amdgcn_mfma_f32_16x16x32_bf16(af[i], wf[j], acc[i][j], 0, 0, 0);
    __syncthreads();
  }
  float bv[4];
#pragma unroll
  for (int j = 0; j < 4; ++j) bv[j] = bias[n0 + wn + 16 * j + l16];
#pragma unroll
  for (int i = 0; i < 4; ++i) {
    int row = m0 + wm + 16 * i + quad * 4;
#pragma unroll
    for (int j = 0; j < 4; ++j) {
      int col = n0 + wn + 16 * j + l16;
#pragma unroll
      for (int r = 0; r < 4; ++r)
        out[(size_t)(row + r) * 1024 + col] = acc[i][j][r] + bv[j];
    }
  }
}

// ---------------- LSTM scan v4: fused single-phase step, 1 barrier/step ----------------
// 1024 thr = 16 waves. lane l: kh=l>>5 (k-half), gsel=(l>>4)&1, j = wave*16 + (l&15).
// Thread computes half-length (128) dots for rows gsel*256+j (gate i/f) and
// +512 (gate g/o). k-half reduce = shfl_xor(32); gate exchange = shfl_xor(16);
// c,h update redundantly on all 4 lane-copies in registers. h double-buffered
// in LDS (2x512B) so the step needs exactly ONE __syncthreads.
// Weights: 96 u32 in VGPR + 32 u32 in LDS per thread (128 KB), as in v3.
#define SCAN_LDS (131072 + 1024)   // wlds + hbuf[2][128] = 132096 B
__global__ __launch_bounds__(1024, 1)
void scan4_kernel(const float* __restrict__ pre_f, const float* __restrict__ pre_r,
                  const u32* __restrict__ whh_f, const u32* __restrict__ whh_r,
                  void* __restrict__ outp, int out_bf16) {
  extern __shared__ char smem[];
  u32* wlds = (u32*)smem;                 // [8][1024][4] u32
  u32* hbuf = (u32*)(smem + 131072);      // [2][128] u32 = 2 x 256 f16
  const int tid = threadIdx.x;
  const int w = tid >> 6, l = tid & 63;
  const int kh = l >> 5;                  // k-half
  const int gsel = (l >> 4) & 1;          // 0: gates {i,g}, 1: gates {f,o}
  const int j = w * 16 + (l & 15);        // hidden index [0,256)
  const int row0 = gsel * 256 + j;        // gate i or f
  const int row1 = row0 + 512;            // gate g or o
  const int chain = blockIdx.x;
  const int dir = chain & 1, b = chain >> 1;
  const float* pre = dir ? pre_r : pre_f;
  const u32* whh = dir ? whh_r : whh_f;   // f16-pair packed [1024][128]

  u32 wreg0[48], wreg1[48];
  {
    const u32* w0p = whh + (size_t)row0 * 128 + kh * 64;
    const u32* w1p = whh + (size_t)row1 * 128 + kh * 64;
#pragma unroll
    for (int c = 0; c < 12; ++c) {
      uint4 a = *(const uint4*)(w0p + c * 4);
      wreg0[c*4+0] = a.x; wreg0[c*4+1] = a.y; wreg0[c*4+2] = a.z; wreg0[c*4+3] = a.w;
      uint4 bq = *(const uint4*)(w1p + c * 4);
      wreg1[c*4+0] = bq.x; wreg1[c*4+1] = bq.y; wreg1[c*4+2] = bq.z; wreg1[c*4+3] = bq.w;
    }
#pragma unroll
    for (int c = 0; c < 4; ++c) {
      *(uint4*)(wlds + ((size_t)c * 1024 + tid) * 4)       = *(const uint4*)(w0p + (12 + c) * 4);
      *(uint4*)(wlds + ((size_t)(4 + c) * 1024 + tid) * 4) = *(const uint4*)(w1p + (12 + c) * 4);
    }
  }
  if (tid < 256) hbuf[tid] = 0u;
  float cst = 0.f;
  // preload pre for t=0 (each thread: its two gate rows)
  {
    const int t0 = dir ? TC_ - 1 : 0;
    const float* pr = pre + ((size_t)b * TC_ + t0) * 1024;
    // fallthrough into loop via cur0/cur1
  }
  const float* pr0 = pre + ((size_t)b * TC_ + (dir ? TC_ - 1 : 0)) * 1024;
  float cur0 = pr0[row0], cur1 = pr0[row1];
  __syncthreads();

  for (int t = 0; t < TC_; ++t) {
    const int tt = dir ? (TC_ - 1 - t) : t;
    const u32* hb = hbuf + (t & 1) * 128 + kh * 64;
    // prefetch next step's pre
    float nxt0 = 0.f, nxt1 = 0.f;
    if (t + 1 < TC_) {
      const int tn = dir ? (TC_ - 2 - t) : (t + 1);
      const float* pr = pre + ((size_t)b * TC_ + tn) * 1024;
      nxt0 = pr[row0]; nxt1 = pr[row1];
    }
    float acc0 = 0.f, acc1 = 0.f;
#pragma unroll
    for (int c = 0; c < 12; ++c) {
      uint4 h4 = *(const uint4*)(hb + c * 4);
      acc0 = dot2(wreg0[c*4+0], h4.x, acc0);
      acc0 = dot2(wreg0[c*4+1], h4.y, acc0);
      acc0 = dot2(wreg0[c*4+2], h4.z, acc0);
      acc0 = dot2(wreg0[c*4+3], h4.w, acc0);
      acc1 = dot2(wreg1[c*4+0], h4.x, acc1);
      acc1 = dot2(wreg1[c*4+1], h4.y, acc1);
      acc1 = dot2(wreg1[c*4+2], h4.z, acc1);
      acc1 = dot2(wreg1[c*4+3], h4.w, acc1);
    }
#pragma unroll
    for (int c = 0; c < 4; ++c) {
      uint4 h4 = *(const uint4*)(hb + (12 + c) * 4);
      uint4 w0 = *(const uint4*)(wlds + ((size_t)c * 1024 + tid) * 4);
      uint4 w1 = *(const uint4*)(wlds + ((size_t)(4 + c) * 1024 + tid) * 4);
      acc0 = dot2(w0.x, h4.x, acc0);
      acc0 = dot2(w0.y, h4.y, acc0);
      acc0 = dot2(w0.z, h4.z, acc0);
      acc0 = dot2(w0.w, h4.w, acc0);
      acc1 = dot2(w1.x, h4.x, acc1);
      acc1 = dot2(w1.y, h4.y, acc1);
      acc1 = dot2(w1.z, h4.z, acc1);
      acc1 = dot2(w1.w, h4.w, acc1);
    }
    // k-half reduction (both copies end with the full dot)
    acc0 += __shfl_xor(acc0, 32);
    acc1 += __shfl_xor(acc1, 32);
    acc0 += cur0;
    acc1 += cur1;
    // activations: a0 = sigm(i or f). a1 = tanh(g) if gsel==0 else sigm(o).
    float a0 = sigmf(acc0);
    float ax = gsel ? -acc1 : 2.f * acc1;
    float e  = __expf(ax);
    float r  = 1.f / (e + 1.f);
    float a1 = gsel ? r : 1.f - 2.f * r;
    // exchange gates across gsel partner (same kh, same j)
    float b0 = __shfl_xor(a0, 16);   // partner's sigm gate
    float b1 = __shfl_xor(a1, 16);   // partner's second gate
    float i_ = gsel ? b0 : a0;
    float f_ = gsel ? a0 : b0;
    float g_ = gsel ? b1 : a1;
    float o_ = gsel ? a1 : b1;
    cst = f_ * cst + i_ * g_;        // identical on all 4 lane-copies of j
    float h = o_ * tanhfast(cst);
    if (l < 16) {                    // one lane-copy per j does the stores
      size_t oi = ((size_t)b * TC_ + tt) * 512 + (size_t)dir * 256 + j;
      if (out_bf16) ((u16*)outp)[oi] = f2bf(h);
      else          ((float*)outp)[oi] = h;
      u16* hw = (u16*)(hbuf + ((t + 1) & 1) * 128);
      hw[j] = __half_as_ushort(__float2half(h));
    }
    cur0 = nxt0; cur1 = nxt1;
    __syncthreads();                 // writes to buf (t+1)&1 visible; reads of buf t&1 done
  }
}

// ---------------- FC heads ----------------
__global__ void fc_init_kernel(const float* __restrict__ fc1_b, const float* __restrict__ fc2_b,
                               float* __restrict__ out) {
  int i = blockIdx.x * 256 + threadIdx.x;
  if (i < 3200) out[i] = fc1_b[i % 100];
  else if (i < 6080) out[i] = fc2_b[(i - 3200) % 90];
}

#define FCK 1024
#define FCSUB 64
__global__ __launch_bounds__(256)
void fc_kernel(const float* __restrict__ flat, const float* __restrict__ w1,
               const float* __restrict__ w2, float* __restrict__ out) {
  __shared__ float fs[32][FCSUB + 1];
  __shared__ float ws[192][FCSUB + 1];
  int tid = threadIdx.x;
  int tn = tid & 31, tb = tid >> 5;
  size_t k0 = (size_t)blockIdx.x * FCK;
  float acc[4][6] = {};
  for (int kc = 0; kc < FCK; kc += FCSUB) {
    __syncthreads();
    for (int idx = tid; idx < 32 * FCSUB; idx += 256) {
      int bb = idx >> 6, j = idx & 63;
      fs[bb][j] = flat[(size_t)bb * 524288 + k0 + kc + j];
    }
    for (int idx = tid; idx < 192 * FCSUB; idx += 256) {
      int n = idx >> 6, j = idx & 63;
      float v = 0.f;
      if (n < 100)      v = w1[(size_t)n * 524288 + k0 + kc + j];
      else if (n < 190) v = w2[(size_t)(n - 100) * 524288 + k0 + kc + j];
      ws[n][j] = v;
    }
    __syncthreads();
    for (int j = 0; j < FCSUB; ++j) {
      float fv[4], wv[6];
#pragma unroll
      for (int m = 0; m < 4; ++m) fv[m] = fs[tb + 8 * m][j];
#pragma unroll
      for (int mm = 0; mm < 6; ++mm) wv[mm] = ws[tn + 32 * mm][j];
#pragma unroll
      for (int m = 0; m < 4; ++m)
#pragma unroll
        for (int mm = 0; mm < 6; ++mm) acc[m][mm] = fmaf(fv[m], wv[mm], acc[m][mm]);
    }
  }
#pragma unroll
  for (int m = 0; m < 4; ++m)
#pragma unroll
    for (int mm = 0; mm < 6; ++mm) {
      int n = tn + 32 * mm, bb = tb + 8 * m;
      if (n < 190) {
        int oi = (n < 100) ? (bb * 100 + n) : (3200 + bb * 90 + (n - 100));
        atomicAdd(out + oi, acc[m][mm]);
      }
    }
}

// ---------------- launcher ----------------
extern "C" void kernel_launch(void* const* d_in, const int* in_sizes, int n_in,
                              void* d_out, int out_size, void* d_ws, size_t ws_size,
                              hipStream_t stream) {
  const float* x       = (const float*)d_in[0];
  const float* conv_w  = (const float*)d_in[1];
  const float* conv_b  = (const float*)d_in[2];
  const float* bn_g    = (const float*)d_in[3];
  const float* bn_bb   = (const float*)d_in[4];
  const float* bn_m    = (const float*)d_in[5];
  const float* bn_v    = (const float*)d_in[6];
  const float* w_ih_f0 = (const float*)d_in[7];
  const float* w_hh_f0 = (const float*)d_in[8];
  const float* b_f0    = (const float*)d_in[9];
  const float* w_ih_r0 = (const float*)d_in[10];
  const float* w_hh_r0 = (const float*)d_in[11];
  const float* b_r0    = (const float*)d_in[12];
  const float* w_ih_f1 = (const float*)d_in[13];
  const float* w_hh_f1 = (const float*)d_in[14];
  const float* b_f1    = (const float*)d_in[15];
  const float* w_ih_r1 = (const float*)d_in[16];
  const float* w_hh_r1 = (const float*)d_in[17];
  const float* b_r1    = (const float*)d_in[18];
  const float* fc1_w   = (const float*)d_in[19];
  const float* fc1_b   = (const float*)d_in[20];
  const float* fc2_w   = (const float*)d_in[21];
  const float* fc2_b   = (const float*)d_in[22];
  float* out = (float*)d_out;

  char* base = (char*)d_ws;
  size_t off = 0;
  auto carve = [&](size_t bytes) -> char* {
    char* p = base + off;
    off += (bytes + 511) & ~(size_t)511;
    return p;
  };
  u16*   ybf   = (u16*)carve((size_t)M_ * 256 * 2);
  u16*   wb_f0 = (u16*)carve((size_t)262144 * 2);
  u16*   wb_r0 = (u16*)carve((size_t)262144 * 2);
  u16*   wb_f1 = (u16*)carve((size_t)524288 * 2);
  u16*   wb_r1 = (u16*)carve((size_t)524288 * 2);
  u16*   wh_f0 = (u16*)carve((size_t)262144 * 2);
  u16*   wh_r0 = (u16*)carve((size_t)262144 * 2);
  u16*   wh_f1 = (u16*)carve((size_t)262144 * 2);
  u16*   wh_r1 = (u16*)carve((size_t)262144 * 2);
  u16*   h0cat = (u16*)carve((size_t)M_ * 512 * 2);
  float* h1cat = (float*)carve((size_t)M_ * 512 * 4);
  float* pre_f = (float*)carve((size_t)M_ * 1024 * 4);
  float* pre_r = (float*)carve((size_t)M_ * 1024 * 4);
  if (off > ws_size) return;

  hipFuncSetAttribute((const void*)scan4_kernel,
                      hipFuncAttributeMaxDynamicSharedMemorySize, SCAN_LDS);

  cast_bf16_kernel<<<1024, 256, 0, stream>>>(w_ih_f0, wb_f0, 262144);
  cast_bf16_kernel<<<1024, 256, 0, stream>>>(w_ih_r0, wb_r0, 262144);
  cast_bf16_kernel<<<2048, 256, 0, stream>>>(w_ih_f1, wb_f1, 524288);
  cast_bf16_kernel<<<2048, 256, 0, stream>>>(w_ih_r1, wb_r1, 524288);
  cast_f16_kernel<<<1024, 256, 0, stream>>>(w_hh_f0, wh_f0, 262144);
  cast_f16_kernel<<<1024, 256, 0, stream>>>(w_hh_r0, wh_r0, 262144);
  cast_f16_kernel<<<1024, 256, 0, stream>>>(w_hh_f1, wh_f1, 262144);
  cast_f16_kernel<<<1024, 256, 0, stream>>>(w_hh_r1, wh_r1, 262144);

  conv_bn_kernel<<<M_, 256, 0, stream>>>(x, conv_w, conv_b, bn_g, bn_bb, bn_m, bn_v, ybf);

  proj_gemm2_kernel<<<dim3(256, 8, 2), 256, 0, stream>>>(
      ybf, wb_f0, wb_r0, b_f0, b_r0, pre_f, pre_r, 256);

  scan4_kernel<<<64, 1024, SCAN_LDS, stream>>>(
      pre_f, pre_r, (const u32*)wh_f0, (const u32*)wh_r0, (void*)h0cat, 1);

  proj_gemm2_kernel<<<dim3(256, 8, 2), 256, 0, stream>>>(
      h0cat, wb_f1, wb_r1, b_f1, b_r1, pre_f, pre_r, 512);

  scan4_kernel<<<64, 1024, SCAN_LDS, stream>>>(
      pre_f, pre_r, (const u32*)wh_f1, (const u32*)wh_r1, (void*)h1cat, 0);

  fc_init_kernel<<<24, 256, 0, stream>>>(fc1_b, fc2_b, out);
  fc_kernel<<<512, 256, 0, stream>>>(h1cat, fc1_w, fc2_w, out);
}